// Round 5
// baseline (170.038 us; speedup 1.0000x reference)
//
#include <hip/hip_runtime.h>
#include <hip/hip_bf16.h>

#define THREADS 256
#define ROWS_PER_BLOCK 8
#define JSPLIT 4
#define EMB_ROWS 5050

typedef _Float16 half2v __attribute__((ext_vector_type(2)));
typedef __fp16   fp16x2 __attribute__((ext_vector_type(2)));

__device__ __forceinline__ half2v pk(float a, float b) {
    fp16x2 r = __builtin_amdgcn_cvt_pkrtz(a, b);   // v_cvt_pkrtz_f16_f32
    return __builtin_bit_cast(half2v, r);
}

// Each block: 8 rows (i) x a 1024-wide slice of columns (j).
// Layer-1 of the MLP in packed f16 (v_pk_fma_f16), layer-2 via v_dot2_f32_f16.
__global__ __launch_bounds__(THREADS, 8) void energy_main_kernel(
    const float* __restrict__ coords,
    const int*   __restrict__ atom_ix,
    const float* __restrict__ charges,
    const float* __restrict__ emb,
    const float* __restrict__ W1,
    const float* __restrict__ b1,
    const float* __restrict__ W2,
    const float* __restrict__ b2,
    float* __restrict__ partials,
    int n_atoms)
{
    __shared__ float s_emb[EMB_ROWS];
    for (int t = threadIdx.x; t < EMB_ROWS; t += THREADS) s_emb[t] = emb[t];

    // Pack MLP weights as f16 pairs over adjacent k: (k=2j, 2j+1).
    half2v A2[8], B2[8], C2[8], U0_2[8], U1_2[8], U2_2[8];
#pragma unroll
    for (int j = 0; j < 8; ++j) {
        A2[j]   = pk(W1[2 * j],      W1[2 * j + 1]);        // W1[0][k]
        B2[j]   = pk(W1[16 + 2 * j], W1[16 + 2 * j + 1]);   // W1[1][k]
        C2[j]   = pk(b1[2 * j],      b1[2 * j + 1]);
        U0_2[j] = pk(W2[3 * (2 * j) + 0], W2[3 * (2 * j + 1) + 0]);
        U1_2[j] = pk(W2[3 * (2 * j) + 1], W2[3 * (2 * j + 1) + 1]);
        U2_2[j] = pk(W2[3 * (2 * j) + 2], W2[3 * (2 * j + 1) + 2]);
    }
    const float bo0 = b2[0], bo1 = b2[1], bo2 = b2[2];

    const int rb   = blockIdx.x / JSPLIT;
    const int js   = blockIdx.x % JSPLIT;
    const int row0 = rb * ROWS_PER_BLOCK;
    const int jlen = n_atoms / JSPLIT;
    const int j0   = js * jlen;

    float xr[ROWS_PER_BLOCK], yr[ROWS_PER_BLOCK], zr[ROWS_PER_BLOCK], qr[ROWS_PER_BLOCK];
    int   br[ROWS_PER_BLOCK];
#pragma unroll
    for (int r = 0; r < ROWS_PER_BLOCK; ++r) {
        const int i = row0 + r;
        xr[r] = coords[3 * i + 0];
        yr[r] = coords[3 * i + 1];
        zr[r] = coords[3 * i + 2];
        qr[r] = charges[i];
        const int a = atom_ix[i];
        br[r] = (a * (a + 1)) >> 1;
    }
    __syncthreads();

    float cacc = 0.0f, ljacc = 0.0f;
    const half2v zero2 = (half2v)(_Float16)0.0f;

#pragma unroll 1
    for (int j = j0 + threadIdx.x; j < j0 + jlen; j += THREADS) {
        const float xj = coords[3 * j + 0];
        const float yj = coords[3 * j + 1];
        const float zj = coords[3 * j + 2];
        const float qj = charges[j];
        const int   aj = atom_ix[j];

#pragma unroll
        for (int r = 0; r < ROWS_PER_BLOCK; ++r) {
            const float dx = xj - xr[r];
            const float dy = yj - yr[r];
            const float dz = zj - zr[r];
            const float sq = fmaf(dx, dx, fmaf(dy, dy, dz * dz));
            // sq==0 (diagonal): rsqrtf(0)=+inf, fminf(inf,10)=10 -> matches
            // the reference's nan_to_num + clamp-to-10 semantics exactly.
            const float rd = fminf(rsqrtf(sq), 10.0f);

            const float e = s_emb[br[r] + aj];
            const float c = qr[r] * qj;
            const half2v e2 = pk(e, e);
            const half2v c2 = pk(c, c);

            float o0 = bo0, o1 = bo1, o2 = bo2;
#pragma unroll
            for (int k = 0; k < 8; ++k) {
                half2v h = B2[k] * c2 + C2[k];            // v_pk_fma_f16
                h = A2[k] * e2 + h;                       // v_pk_fma_f16
                h = __builtin_elementwise_max(h, zero2);  // v_pk_max_f16
                o0 = __builtin_amdgcn_fdot2(h, U0_2[k], o0, false);
                o1 = __builtin_amdgcn_fdot2(h, U1_2[k], o1, false);
                o2 = __builtin_amdgcn_fdot2(h, U2_2[k], o2, false);
            }

            cacc = fmaf(o0, rd, cacc);
            const float sr  = o1 * rd;
            const float sr2 = sr * sr;
            const float sr6 = sr2 * sr2 * sr2;
            ljacc = fmaf(o2, fmaf(sr6, sr6, -sr6), ljacc);
        }
    }

    // Deterministic in-block reduction: wave shuffle, then LDS across waves.
#pragma unroll
    for (int off = 32; off > 0; off >>= 1) {
        cacc  += __shfl_down(cacc, off, 64);
        ljacc += __shfl_down(ljacc, off, 64);
    }
    __shared__ float s_c[THREADS / 64], s_l[THREADS / 64];
    const int wave = threadIdx.x >> 6;
    const int lane = threadIdx.x & 63;
    if (lane == 0) { s_c[wave] = cacc; s_l[wave] = ljacc; }
    __syncthreads();
    if (threadIdx.x == 0) {
        float ct = 0.0f, lt = 0.0f;
#pragma unroll
        for (int w = 0; w < THREADS / 64; ++w) { ct += s_c[w]; lt += s_l[w]; }
        partials[2 * blockIdx.x + 0] = ct;
        partials[2 * blockIdx.x + 1] = lt;
    }
}

// Final reduction over block partials (fixed order -> deterministic).
__global__ __launch_bounds__(THREADS, 1) void energy_reduce_kernel(
    const float* __restrict__ partials, int nblocks,
    const float* __restrict__ bias, float* __restrict__ out)
{
    float ct = 0.0f, lt = 0.0f;
    for (int b = threadIdx.x; b < nblocks; b += THREADS) {
        ct += partials[2 * b + 0];
        lt += partials[2 * b + 1];
    }
#pragma unroll
    for (int off = 32; off > 0; off >>= 1) {
        ct += __shfl_down(ct, off, 64);
        lt += __shfl_down(lt, off, 64);
    }
    __shared__ float s_c[THREADS / 64], s_l[THREADS / 64];
    const int wave = threadIdx.x >> 6;
    const int lane = threadIdx.x & 63;
    if (lane == 0) { s_c[wave] = ct; s_l[wave] = lt; }
    __syncthreads();
    if (threadIdx.x == 0) {
        float c = 0.0f, l = 0.0f;
#pragma unroll
        for (int w = 0; w < THREADS / 64; ++w) { c += s_c[w]; l += s_l[w]; }
        // COULOMB_CONSTANT = -1, EV = 1.602e-19
        out[0] = -c + 1.602e-19f * l + bias[0];
    }
}

extern "C" void kernel_launch(void* const* d_in, const int* in_sizes, int n_in,
                              void* d_out, int out_size, void* d_ws, size_t ws_size,
                              hipStream_t stream)
{
    const float* coords  = (const float*)d_in[0];
    const int*   atom_ix = (const int*)d_in[1];
    const float* charges = (const float*)d_in[2];
    const float* emb     = (const float*)d_in[3];
    const float* W1      = (const float*)d_in[4];
    const float* b1      = (const float*)d_in[5];
    const float* W2      = (const float*)d_in[6];
    const float* b2      = (const float*)d_in[7];
    const float* bias    = (const float*)d_in[8];

    float* out      = (float*)d_out;
    float* partials = (float*)d_ws;

    const int n       = in_sizes[1];                       // 4096 atoms
    const int nblocks = (n / ROWS_PER_BLOCK) * JSPLIT;     // 2048 blocks

    energy_main_kernel<<<nblocks, THREADS, 0, stream>>>(
        coords, atom_ix, charges, emb, W1, b1, W2, b2, partials, n);
    energy_reduce_kernel<<<1, THREADS, 0, stream>>>(partials, nblocks, bias, out);
}

// Round 6
// 44.333 us; speedup vs baseline: 3.8355x; 3.8355x over previous
//
#include <hip/hip_runtime.h>
#include <hip/hip_bf16.h>

#define THREADS 256
#define ROWS_PER_BLOCK 8
#define JSPLIT 4
#define EMB_ROWS 5050

typedef _Float16 half2v __attribute__((ext_vector_type(2)));
typedef __fp16   fp16x2 __attribute__((ext_vector_type(2)));

__device__ __forceinline__ half2v pk(float a, float b) {
    fp16x2 r = __builtin_amdgcn_cvt_pkrtz(a, b);   // v_cvt_pkrtz_f16_f32
    return __builtin_bit_cast(half2v, r);
}

// Each block: 8 rows (i) x a 1024-wide slice of columns (j).
// Layer-1 of the MLP in packed f16 (v_pk_fma_f16), layer-2 via v_dot2_f32_f16.
// NOTE: launch_bounds min-waves/EU kept at 4 (VGPR cap 128). Asking for 8
// caps VGPR at 64 -> compiler spills the 48-reg weight arrays to scratch
// (R5: 444 MB FETCH/dispatch, 171 us). With natural VGPR=54 <= 64 the HW
// still co-resides 8 blocks/CU (LDS 20KiB x 8 = 160KiB exact fit).
__global__ __launch_bounds__(THREADS, 4) void energy_main_kernel(
    const float* __restrict__ coords,
    const int*   __restrict__ atom_ix,
    const float* __restrict__ charges,
    const float* __restrict__ emb,
    const float* __restrict__ W1,
    const float* __restrict__ b1,
    const float* __restrict__ W2,
    const float* __restrict__ b2,
    float* __restrict__ partials,
    int n_atoms)
{
    __shared__ float s_emb[EMB_ROWS];
    for (int t = threadIdx.x; t < EMB_ROWS; t += THREADS) s_emb[t] = emb[t];

    // Pack MLP weights as f16 pairs over adjacent k: (k=2j, 2j+1).
    half2v A2[8], B2[8], C2[8], U0_2[8], U1_2[8], U2_2[8];
#pragma unroll
    for (int j = 0; j < 8; ++j) {
        A2[j]   = pk(W1[2 * j],      W1[2 * j + 1]);        // W1[0][k]
        B2[j]   = pk(W1[16 + 2 * j], W1[16 + 2 * j + 1]);   // W1[1][k]
        C2[j]   = pk(b1[2 * j],      b1[2 * j + 1]);
        U0_2[j] = pk(W2[3 * (2 * j) + 0], W2[3 * (2 * j + 1) + 0]);
        U1_2[j] = pk(W2[3 * (2 * j) + 1], W2[3 * (2 * j + 1) + 1]);
        U2_2[j] = pk(W2[3 * (2 * j) + 2], W2[3 * (2 * j + 1) + 2]);
    }
    const float bo0 = b2[0], bo1 = b2[1], bo2 = b2[2];

    const int rb   = blockIdx.x / JSPLIT;
    const int js   = blockIdx.x % JSPLIT;
    const int row0 = rb * ROWS_PER_BLOCK;
    const int jlen = n_atoms / JSPLIT;
    const int j0   = js * jlen;

    float xr[ROWS_PER_BLOCK], yr[ROWS_PER_BLOCK], zr[ROWS_PER_BLOCK], qr[ROWS_PER_BLOCK];
    int   br[ROWS_PER_BLOCK];
#pragma unroll
    for (int r = 0; r < ROWS_PER_BLOCK; ++r) {
        const int i = row0 + r;
        xr[r] = coords[3 * i + 0];
        yr[r] = coords[3 * i + 1];
        zr[r] = coords[3 * i + 2];
        qr[r] = charges[i];
        const int a = atom_ix[i];
        br[r] = (a * (a + 1)) >> 1;
    }
    __syncthreads();

    float cacc = 0.0f, ljacc = 0.0f;
    const half2v zero2 = (half2v)(_Float16)0.0f;

#pragma unroll 1
    for (int j = j0 + threadIdx.x; j < j0 + jlen; j += THREADS) {
        const float xj = coords[3 * j + 0];
        const float yj = coords[3 * j + 1];
        const float zj = coords[3 * j + 2];
        const float qj = charges[j];
        const int   aj = atom_ix[j];

#pragma unroll
        for (int r = 0; r < ROWS_PER_BLOCK; ++r) {
            const float dx = xj - xr[r];
            const float dy = yj - yr[r];
            const float dz = zj - zr[r];
            const float sq = fmaf(dx, dx, fmaf(dy, dy, dz * dz));
            // sq==0 (diagonal): rsqrtf(0)=+inf, fminf(inf,10)=10 -> matches
            // the reference's nan_to_num + clamp-to-10 semantics exactly.
            const float rd = fminf(rsqrtf(sq), 10.0f);

            const float e = s_emb[br[r] + aj];
            const float c = qr[r] * qj;
            const half2v e2 = pk(e, e);
            const half2v c2 = pk(c, c);

            float o0 = bo0, o1 = bo1, o2 = bo2;
#pragma unroll
            for (int k = 0; k < 8; ++k) {
                half2v h = B2[k] * c2 + C2[k];            // v_pk_fma_f16
                h = A2[k] * e2 + h;                       // v_pk_fma_f16
                h = __builtin_elementwise_max(h, zero2);  // v_pk_max_f16
                o0 = __builtin_amdgcn_fdot2(h, U0_2[k], o0, false);
                o1 = __builtin_amdgcn_fdot2(h, U1_2[k], o1, false);
                o2 = __builtin_amdgcn_fdot2(h, U2_2[k], o2, false);
            }

            cacc = fmaf(o0, rd, cacc);
            const float sr  = o1 * rd;
            const float sr2 = sr * sr;
            const float sr6 = sr2 * sr2 * sr2;
            ljacc = fmaf(o2, fmaf(sr6, sr6, -sr6), ljacc);
        }
    }

    // Deterministic in-block reduction: wave shuffle, then LDS across waves.
#pragma unroll
    for (int off = 32; off > 0; off >>= 1) {
        cacc  += __shfl_down(cacc, off, 64);
        ljacc += __shfl_down(ljacc, off, 64);
    }
    __shared__ float s_c[THREADS / 64], s_l[THREADS / 64];
    const int wave = threadIdx.x >> 6;
    const int lane = threadIdx.x & 63;
    if (lane == 0) { s_c[wave] = cacc; s_l[wave] = ljacc; }
    __syncthreads();
    if (threadIdx.x == 0) {
        float ct = 0.0f, lt = 0.0f;
#pragma unroll
        for (int w = 0; w < THREADS / 64; ++w) { ct += s_c[w]; lt += s_l[w]; }
        partials[2 * blockIdx.x + 0] = ct;
        partials[2 * blockIdx.x + 1] = lt;
    }
}

// Final reduction over block partials (fixed order -> deterministic).
__global__ __launch_bounds__(THREADS, 1) void energy_reduce_kernel(
    const float* __restrict__ partials, int nblocks,
    const float* __restrict__ bias, float* __restrict__ out)
{
    float ct = 0.0f, lt = 0.0f;
    for (int b = threadIdx.x; b < nblocks; b += THREADS) {
        ct += partials[2 * b + 0];
        lt += partials[2 * b + 1];
    }
#pragma unroll
    for (int off = 32; off > 0; off >>= 1) {
        ct += __shfl_down(ct, off, 64);
        lt += __shfl_down(lt, off, 64);
    }
    __shared__ float s_c[THREADS / 64], s_l[THREADS / 64];
    const int wave = threadIdx.x >> 6;
    const int lane = threadIdx.x & 63;
    if (lane == 0) { s_c[wave] = ct; s_l[wave] = lt; }
    __syncthreads();
    if (threadIdx.x == 0) {
        float c = 0.0f, l = 0.0f;
#pragma unroll
        for (int w = 0; w < THREADS / 64; ++w) { c += s_c[w]; l += s_l[w]; }
        // COULOMB_CONSTANT = -1, EV = 1.602e-19
        out[0] = -c + 1.602e-19f * l + bias[0];
    }
}

extern "C" void kernel_launch(void* const* d_in, const int* in_sizes, int n_in,
                              void* d_out, int out_size, void* d_ws, size_t ws_size,
                              hipStream_t stream)
{
    const float* coords  = (const float*)d_in[0];
    const int*   atom_ix = (const int*)d_in[1];
    const float* charges = (const float*)d_in[2];
    const float* emb     = (const float*)d_in[3];
    const float* W1      = (const float*)d_in[4];
    const float* b1      = (const float*)d_in[5];
    const float* W2      = (const float*)d_in[6];
    const float* b2      = (const float*)d_in[7];
    const float* bias    = (const float*)d_in[8];

    float* out      = (float*)d_out;
    float* partials = (float*)d_ws;

    const int n       = in_sizes[1];                       // 4096 atoms
    const int nblocks = (n / ROWS_PER_BLOCK) * JSPLIT;     // 2048 blocks

    energy_main_kernel<<<nblocks, THREADS, 0, stream>>>(
        coords, atom_ix, charges, emb, W1, b1, W2, b2, partials, n);
    energy_reduce_kernel<<<1, THREADS, 0, stream>>>(partials, nblocks, bias, out);
}

// Round 7
// 43.814 us; speedup vs baseline: 3.8809x; 1.0118x over previous
//
#include <hip/hip_runtime.h>
#include <hip/hip_bf16.h>
#include <stdint.h>

#define THREADS 256
#define ROWS_PER_BLOCK 8
#define JSPLIT 4
#define MAXEL 100
#define EMB_ROWS 5050

typedef _Float16 half2v __attribute__((ext_vector_type(2)));
typedef __fp16   fp16x2 __attribute__((ext_vector_type(2)));
typedef unsigned int uint4v __attribute__((ext_vector_type(4)));

__device__ __forceinline__ half2v pk(float a, float b) {
    fp16x2 r = __builtin_amdgcn_cvt_pkrtz(a, b);   // v_cvt_pkrtz_f16_f32
    return __builtin_bit_cast(half2v, r);
}
__device__ __forceinline__ half2v pkfma(half2v a, half2v b, half2v c) {
    return __builtin_elementwise_fma(a, b, c);     // v_pk_fma_f16 guaranteed
}

// Each block: 8 rows (i) x a 1024-wide slice of columns (j).
// Layer-1 e-dependence is pre-folded into an LDS table per (r, aj):
//   a_k[r][aj] = emb[tri(atom_ix[i_r]) + aj] * A_k + b1_k   (f16, k-packed)
// so per pair layer-1 is t_k = c * B_k + a_k (one pk_fma per k-pair).
// Layer-2 via v_dot2_f32_f16 into f32 accumulators.
__global__ __launch_bounds__(THREADS, 4) void energy_main_kernel(
    const float* __restrict__ coords,
    const int*   __restrict__ atom_ix,
    const float* __restrict__ charges,
    const float* __restrict__ emb,
    const float* __restrict__ W1,
    const float* __restrict__ b1,
    const float* __restrict__ W2,
    const float* __restrict__ b2,
    float* __restrict__ partials,
    int n_atoms)
{
    // k-packed weights (uniform -> SGPR; each consumer reads <=1 SGPR operand)
    half2v A2[8], B2[8], C2[8], U0_2[8], U1_2[8], U2_2[8];
#pragma unroll
    for (int p = 0; p < 8; ++p) {
        A2[p]   = pk(W1[2 * p],      W1[2 * p + 1]);        // W1[0][k]
        B2[p]   = pk(W1[16 + 2 * p], W1[16 + 2 * p + 1]);   // W1[1][k]
        C2[p]   = pk(b1[2 * p],      b1[2 * p + 1]);
        U0_2[p] = pk(W2[3 * (2 * p) + 0], W2[3 * (2 * p + 1) + 0]);
        U1_2[p] = pk(W2[3 * (2 * p) + 1], W2[3 * (2 * p + 1) + 1]);
        U2_2[p] = pk(W2[3 * (2 * p) + 2], W2[3 * (2 * p + 1) + 2]);
    }
    const float bo0 = b2[0], bo1 = b2[1], bo2 = b2[2];

    const int rb   = blockIdx.x / JSPLIT;
    const int js   = blockIdx.x % JSPLIT;
    const int row0 = rb * ROWS_PER_BLOCK;
    const int jlen = n_atoms / JSPLIT;
    const int j0   = js * jlen;

    // ---- L1 table: [ROWS][MAXEL][8 half2] = 25.6 KB ----
    __shared__ uint32_t s_tab[ROWS_PER_BLOCK * MAXEL * 8];
    for (int idx = threadIdx.x; idx < ROWS_PER_BLOCK * MAXEL; idx += THREADS) {
        const int r = idx / MAXEL;
        const int a = idx - r * MAXEL;
        const int ai = atom_ix[row0 + r];
        const float e = emb[((ai * (ai + 1)) >> 1) + a];
        const half2v e2 = pk(e, e);
        uint4v w0, w1;
#pragma unroll
        for (int p = 0; p < 4; ++p)
            w0[p] = __builtin_bit_cast(uint32_t, pkfma(e2, A2[p], C2[p]));
#pragma unroll
        for (int p = 0; p < 4; ++p)
            w1[p] = __builtin_bit_cast(uint32_t, pkfma(e2, A2[p + 4], C2[p + 4]));
        *(uint4v*)&s_tab[idx * 8 + 0] = w0;
        *(uint4v*)&s_tab[idx * 8 + 4] = w1;
    }

    float xr[ROWS_PER_BLOCK], yr[ROWS_PER_BLOCK], zr[ROWS_PER_BLOCK], qr[ROWS_PER_BLOCK];
#pragma unroll
    for (int r = 0; r < ROWS_PER_BLOCK; ++r) {
        const int i = row0 + r;
        xr[r] = coords[3 * i + 0];
        yr[r] = coords[3 * i + 1];
        zr[r] = coords[3 * i + 2];
        qr[r] = charges[i];
    }
    __syncthreads();

    float cacc = 0.0f, ljacc = 0.0f;
    const half2v zero2 = (half2v)(_Float16)0.0f;

#pragma unroll 1
    for (int j = j0 + threadIdx.x; j < j0 + jlen; j += THREADS) {
        const float xj = coords[3 * j + 0];
        const float yj = coords[3 * j + 1];
        const float zj = coords[3 * j + 2];
        const float qj = charges[j];
        const int   tb = atom_ix[j] * 8;   // dword index into a row of s_tab

#pragma unroll
        for (int r = 0; r < ROWS_PER_BLOCK; ++r) {
            const float dx = xj - xr[r];
            const float dy = yj - yr[r];
            const float dz = zj - zr[r];
            const float sq = fmaf(dx, dx, fmaf(dy, dy, dz * dz));
            // sq==0 (diagonal): rsqrtf(0)=+inf, fminf(inf,10)=10 -> matches
            // the reference's nan_to_num + clamp-to-10 semantics exactly.
            const float rd = fminf(rsqrtf(sq), 10.0f);

            const float c = qr[r] * qj;
            const half2v c2 = pk(c, c);

            // a_k table: constant per-r offset folds into ds_read offset:
            const uint4v w0 = *(const uint4v*)&s_tab[r * MAXEL * 8 + tb + 0];
            const uint4v w1 = *(const uint4v*)&s_tab[r * MAXEL * 8 + tb + 4];

            float o0 = bo0, o1 = bo1, o2 = bo2;
#pragma unroll
            for (int p = 0; p < 8; ++p) {
                const uint32_t aw = (p < 4) ? w0[p] : w1[p - 4];   // static select
                half2v t = pkfma(c2, B2[p], __builtin_bit_cast(half2v, aw));
                t = __builtin_elementwise_max(t, zero2);           // v_pk_max_f16
                o0 = __builtin_amdgcn_fdot2(t, U0_2[p], o0, false);
                o1 = __builtin_amdgcn_fdot2(t, U1_2[p], o1, false);
                o2 = __builtin_amdgcn_fdot2(t, U2_2[p], o2, false);
            }

            cacc = fmaf(o0, rd, cacc);
            const float sr  = o1 * rd;
            const float sr2 = sr * sr;
            const float sr6 = sr2 * sr2 * sr2;
            ljacc = fmaf(o2, fmaf(sr6, sr6, -sr6), ljacc);
        }
    }

    // Deterministic in-block reduction: wave shuffle, then LDS across waves.
#pragma unroll
    for (int off = 32; off > 0; off >>= 1) {
        cacc  += __shfl_down(cacc, off, 64);
        ljacc += __shfl_down(ljacc, off, 64);
    }
    __shared__ float s_c[THREADS / 64], s_l[THREADS / 64];
    const int wave = threadIdx.x >> 6;
    const int lane = threadIdx.x & 63;
    if (lane == 0) { s_c[wave] = cacc; s_l[wave] = ljacc; }
    __syncthreads();
    if (threadIdx.x == 0) {
        float ct = 0.0f, lt = 0.0f;
#pragma unroll
        for (int w = 0; w < THREADS / 64; ++w) { ct += s_c[w]; lt += s_l[w]; }
        partials[2 * blockIdx.x + 0] = ct;
        partials[2 * blockIdx.x + 1] = lt;
    }
}

// Final reduction over block partials (fixed order -> deterministic).
__global__ __launch_bounds__(THREADS, 1) void energy_reduce_kernel(
    const float* __restrict__ partials, int nblocks,
    const float* __restrict__ bias, float* __restrict__ out)
{
    float ct = 0.0f, lt = 0.0f;
    for (int b = threadIdx.x; b < nblocks; b += THREADS) {
        ct += partials[2 * b + 0];
        lt += partials[2 * b + 1];
    }
#pragma unroll
    for (int off = 32; off > 0; off >>= 1) {
        ct += __shfl_down(ct, off, 64);
        lt += __shfl_down(lt, off, 64);
    }
    __shared__ float s_c[THREADS / 64], s_l[THREADS / 64];
    const int wave = threadIdx.x >> 6;
    const int lane = threadIdx.x & 63;
    if (lane == 0) { s_c[wave] = ct; s_l[wave] = lt; }
    __syncthreads();
    if (threadIdx.x == 0) {
        float c = 0.0f, l = 0.0f;
#pragma unroll
        for (int w = 0; w < THREADS / 64; ++w) { c += s_c[w]; l += s_l[w]; }
        // COULOMB_CONSTANT = -1, EV = 1.602e-19
        out[0] = -c + 1.602e-19f * l + bias[0];
    }
}

extern "C" void kernel_launch(void* const* d_in, const int* in_sizes, int n_in,
                              void* d_out, int out_size, void* d_ws, size_t ws_size,
                              hipStream_t stream)
{
    const float* coords  = (const float*)d_in[0];
    const int*   atom_ix = (const int*)d_in[1];
    const float* charges = (const float*)d_in[2];
    const float* emb     = (const float*)d_in[3];
    const float* W1      = (const float*)d_in[4];
    const float* b1      = (const float*)d_in[5];
    const float* W2      = (const float*)d_in[6];
    const float* b2      = (const float*)d_in[7];
    const float* bias    = (const float*)d_in[8];

    float* out      = (float*)d_out;
    float* partials = (float*)d_ws;

    const int n       = in_sizes[1];                       // 4096 atoms
    const int nblocks = (n / ROWS_PER_BLOCK) * JSPLIT;     // 2048 blocks

    energy_main_kernel<<<nblocks, THREADS, 0, stream>>>(
        coords, atom_ix, charges, emb, W1, b1, W2, b2, partials, n);
    energy_reduce_kernel<<<1, THREADS, 0, stream>>>(partials, nblocks, bias, out);
}